// Round 7
// baseline (271.670 us; speedup 1.0000x reference)
//
#include <hip/hip_runtime.h>

// NeighbourCovariance: per vertex v, gather K=40 neighbors, weight features by
// exp(-10*distsq), compute per-feature weighted mean (C=3) and covariance (3x3).
// Output layout per vertex: [cov (F*9)] ++ [means (F*3)] = 384 floats.
//
// R9: L2-footprint attack. R8 (fp16 gather) gained only ~9 us vs the byte-model's
// 22 -> bytes alone don't govern; the gather still capacity-misses the 4 MB
// per-XCD L2 (fp16 features = 6.4 MB). Fix: split the feature columns in HALF
// temporally. VPB=16, 256 threads = 16 v x 16 f-slots; 640 pairs staged once;
// pass A gathers only f in [0,16) (3.2 MB footprint -> fits per-XCD L2, random
// gather becomes L2-hit), writeback, then pass B for f in [16,32). Streams are
// read ONCE; total bytes/VALU identical to R8 -- only temporal locality changes.
//
//  Phase 1: 640 (v,k) pairs; NT stream loads of nidx/distsq, one exp per pair,
//           coord gather; stage (w,x,y,z) + feature row offset in LDS.
//  Pass A/B: lane=(v, f-half slot); 40 x {b128 broadcast moment read + 32B fp16
//           row-segment gather + 18 VALU}; results staged in LDS (12288 B),
//           coalesced 16B NT writeback of that half's cov/means regions.
//
// LDS: wxyz 10240 + joff 2560 + stage 12288 = 25088 B -> 6 blocks/CU, 24 waves
// (R5 showed 24 waves performs == 32 waves for this kernel).
// Pass 1 (cvt f32->fp16 into d_ws) unchanged from R8; f32 fallback if no ws.

constexpr int K = 40;
constexpr int C = 3;
constexpr int F = 32;
constexpr float EPS = 1e-3f;
constexpr float DIST_SCALE = 10.0f;
constexpr int OUT_PER_V = F * C * C + F * C; // 384 floats = 96 float4
constexpr int VPB = 16;                       // vertices per 256-thread block
constexpr int PAIRS = VPB * K;                // 640
constexpr int STAGE_F4 = VPB * 48;            // 16 v * 192 floats = 768 float4

typedef float    floatx4 __attribute__((ext_vector_type(4)));  // nt-store ok
typedef float    f32x8   __attribute__((ext_vector_type(8)));
typedef _Float16 f16x8   __attribute__((ext_vector_type(8)));

// ---- Pass 0: features f32 -> fp16 (12.8 MB -> 6.4 MB), 8 elems/thread ----
__global__ __launch_bounds__(256) void cvt_kernel(
    const float* __restrict__ in, _Float16* __restrict__ out16, int n8)
{
    const int i = blockIdx.x * 256 + threadIdx.x;
    if (i < n8) {
        const f32x8 v = __builtin_nontemporal_load((const f32x8*)in + i);
        const f16x8 o = __builtin_convertvector(v, f16x8);
        *((f16x8*)out16 + i) = o;   // cached store: re-read by main kernel
    }
}

// ---- Main kernel, templated on feature type ----
template <typename FT>
__global__ __launch_bounds__(256) void neighcov_kernel(
    const float* __restrict__ coords,    // V x 3
    const float* __restrict__ distsq,    // V x K
    const FT*    __restrict__ features,  // V x F (f32 or fp16)
    const int*   __restrict__ nidx,      // V x K
    float* __restrict__ out,             // V x 384
    int V)
{
    __shared__ float4  s_wxyz[PAIRS];     // (w, x, y, z) per (v,k)      10240 B
    __shared__ int     s_joff[PAIRS];     // j*F element offset           2560 B
    __shared__ floatx4 s_stage[STAGE_F4]; // half-output stage           12288 B

    const int tid   = threadIdx.x;
    const int vbase = blockIdx.x * VPB;
    const long long total_pairs = (long long)V * K;

    // ---- Phase 1: stage weights/coords, 640 pairs (streams read ONCE) ----
    #pragma unroll
    for (int p = tid; p < PAIRS; p += 256) {
        const long long gp = (long long)vbase * K + p;
        int idx = -1;
        float d = 0.f;
        if (gp < total_pairs) {
            idx = __builtin_nontemporal_load(nidx + gp);    // coalesced, single-use
            d   = __builtin_nontemporal_load(distsq + gp);  // coalesced, single-use
        }
        const bool valid = (idx >= 0);
        const int j = valid ? idx : 0;
        const float w = valid ? __expf(-DIST_SCALE * d) : 0.f;  // w==0 = invalid
        const float x = coords[(size_t)j * 3 + 0];
        const float y = coords[(size_t)j * 3 + 1];
        const float z = coords[(size_t)j * 3 + 2];
        s_wxyz[p] = make_float4(w, x, y, z);
        s_joff[p] = j * F;
    }
    __syncthreads();

    // ---- Passes A/B: lane = (vertex, feature-slot within half) ----
    const int fl   = tid & 15;   // feature slot within half
    const int vloc = tid >> 4;   // 0..15
    const float4* wp = &s_wxyz[vloc * K];
    const int*    jp = &s_joff[vloc * K];
    const int rem_v = V - vbase;          // >= 1
    floatx4* o4 = (floatx4*)(out + (size_t)vbase * OUT_PER_V);

    #pragma unroll
    for (int half = 0; half < 2; ++half) {
        const int f = half * 16 + fl;

        float wsum = 0.f;
        float m0 = 0.f, m1 = 0.f, m2 = 0.f;
        float s00 = 0.f, s01 = 0.f, s02 = 0.f, s11 = 0.f, s12 = 0.f, s22 = 0.f;

        #pragma unroll 8
        for (int k = 0; k < K; ++k) {
            const float4 q = wp[k];            // b128 broadcast (4 addrs/wave: free)
            const int jo   = jp[k];            // broadcast LDS read
            const float feat = (float)features[jo + f];  // 32B row-segment gather
            const float fw = q.x * feat;       // w==0 encodes invalid neighbor
            const float x = q.y, y = q.z, z = q.w;
            const float fx = fw * x, fy = fw * y, fz = fw * z;
            wsum += fw;
            m0 += fx;        m1 += fy;        m2 += fz;
            s00 += fx * x;   s01 += fx * y;   s02 += fx * z;
            s11 += fy * y;   s12 += fy * z;   s22 += fz * z;
        }

        const float inv = 1.f / (wsum + EPS);
        const float mu0 = m0 * inv, mu1 = m1 * inv, mu2 = m2 * inv;
        const float c00 = s00 * inv - mu0 * mu0;
        const float c01 = s01 * inv - mu0 * mu1;
        const float c02 = s02 * inv - mu0 * mu2;
        const float c11 = s11 * inv - mu1 * mu1;
        const float c12 = s12 * inv - mu1 * mu2;
        const float c22 = s22 * inv - mu2 * mu2;

        // Stage this half's results: per vertex 192 floats = [cov-half 144 |
        // means-half 48]. Strides 9/3 odd -> near-free bank permutation.
        float* s_out = (float*)s_stage;
        float* so = s_out + vloc * 192 + fl * 9;
        so[0] = c00; so[1] = c01; so[2] = c02;
        so[3] = c01; so[4] = c11; so[5] = c12;
        so[6] = c02; so[7] = c12; so[8] = c22;
        float* sm = s_out + vloc * 192 + 144 + fl * 3;
        sm[0] = mu0; sm[1] = mu1; sm[2] = mu2;

        __syncthreads();

        // Coalesced NT writeback of this half's regions.
        // Per vertex (96 f4 total): cov half A = f4 [0,36), half B = [36,72);
        // means half A = [72,84), half B = [84,96).
        #pragma unroll
        for (int g = tid; g < STAGE_F4; g += 256) {
            const int v = g / 48;
            const int r = g - v * 48;
            if (v < rem_v) {
                const int dst = v * 96 + (r < 36 ? half * 36 + r
                                                 : 72 + half * 12 + (r - 36));
                __builtin_nontemporal_store(s_stage[g], o4 + dst);
            }
        }

        __syncthreads();  // s_stage reuse by next half
    }
}

extern "C" void kernel_launch(void* const* d_in, const int* in_sizes, int n_in,
                              void* d_out, int out_size, void* d_ws, size_t ws_size,
                              hipStream_t stream) {
    const float* coords   = (const float*)d_in[0];
    const float* distsq   = (const float*)d_in[1];
    const float* features = (const float*)d_in[2];
    const int*   nidx     = (const int*)d_in[3];
    float* out = (float*)d_out;

    const int V = in_sizes[0] / C;            // coordinates is V x 3
    const int blocks = (V + VPB - 1) / VPB;   // 16 vertices per 256-thread block

    const size_t need = (size_t)V * F * sizeof(_Float16);
    const int nelem = V * F;
    if (ws_size >= need && (nelem & 7) == 0) {
        _Float16* feat16 = (_Float16*)d_ws;
        const int n8 = nelem / 8;
        cvt_kernel<<<(n8 + 255) / 256, 256, 0, stream>>>(features, feat16, n8);
        neighcov_kernel<_Float16><<<blocks, 256, 0, stream>>>(
            coords, distsq, feat16, nidx, out, V);
    } else {
        neighcov_kernel<float><<<blocks, 256, 0, stream>>>(
            coords, distsq, features, nidx, out, V);
    }
}

// Round 8
// 271.617 us; speedup vs baseline: 1.0002x; 1.0002x over previous
//
#include <hip/hip_runtime.h>

// NeighbourCovariance: per vertex v, gather K=40 neighbors, weight features by
// exp(-10*distsq), compute per-feature weighted mean (C=3) and covariance (3x3).
// Output layout per vertex: [cov (F*9)] ++ [means (F*3)] = 384 floats.
//
// R10: line-granularity L2-footprint attack. R9 (column split within rows)
// RAISED fetch 232->290 MB: caches move 128B lines, so half-columns of random
// 64B fp16 rows still drag the whole 6.4 MB per pass, twice. Fix: cvt kernel
// writes TWO SEPARATE fp16 planes lo[V][16], hi[V][16] (3.2 MB each). Pass A
// gathers only plane lo -> line footprint 3.2 MB FITS the 4 MB per-XCD L2
// (random gather becomes L2-hit after compulsory fill); pass B plane hi.
// Streams read once; total VALU unchanged. Also fixes R9's 1.2M LDS bank
// conflicts: s_wxyz padded to stride K+1 (656 B -> the 4 per-wave broadcast
// groups start on banks 0/4/8/12, disjoint quads).
//
//  Phase 1: 640 (v,k) pairs; NT stream loads of nidx/distsq, one exp per pair,
//           coord gather; stage (w,x,y,z) + j*16 plane row offset in LDS.
//  Pass A/B: lane=(v, f-slot 0..15); 40 x {b128 broadcast moment read + 32B
//           fp16 plane-row gather + 18 VALU}; stage half-output in LDS,
//           coalesced 16B NT writeback of that half's cov/means regions.
//
// LDS: wxyz 16*41*16=10496 + joff 2560 + stage 12288 = 25344 B
//      -> 6 blocks/CU, 24 waves/CU (R5: 24 waves == 32 waves here).
// f32 fallback (R4 structure, 95 us) if ws too small.

constexpr int K = 40;
constexpr int C = 3;
constexpr int F = 32;
constexpr int FH = 16;                        // features per half-plane
constexpr float EPS = 1e-3f;
constexpr float DIST_SCALE = 10.0f;
constexpr int OUT_PER_V = F * C * C + F * C;  // 384 floats = 96 float4
constexpr int VPB = 16;                       // vertices per 256-thread block
constexpr int PAIRS = VPB * K;                // 640
constexpr int WSTRIDE = K + 1;                // padded moment stride (bank fix)
constexpr int STAGE_F4 = VPB * 48;            // 16 v * 192 floats = 768 float4

typedef float    floatx4 __attribute__((ext_vector_type(4)));  // nt-store ok
typedef float    f32x8   __attribute__((ext_vector_type(8)));
typedef _Float16 f16x8   __attribute__((ext_vector_type(8)));

// ---- Pass 0: features f32 -> two fp16 half-planes (3.2 MB each) ----
// thread i: row v=i>>2, quarter q=i&3 (8 cols). q<2 -> lo plane, else hi.
__global__ __launch_bounds__(256) void cvt_kernel(
    const float* __restrict__ in, _Float16* __restrict__ lo,
    _Float16* __restrict__ hi, int n4)   // n4 = V*4
{
    const int i = blockIdx.x * 256 + threadIdx.x;
    if (i >= n4) return;
    const int v = i >> 2, q = i & 3;
    const f32x8 x = __builtin_nontemporal_load((const f32x8*)in + i);
    const f16x8 o = __builtin_convertvector(x, f16x8);
    _Float16* dst = (q < 2 ? lo : hi) + (size_t)v * FH + (q & 1) * 8;
    *(f16x8*)dst = o;   // cached store: re-read by main kernel
}

// ---- Main kernel: fp16 two-plane, two-pass ----
__global__ __launch_bounds__(256) void neighcov_split(
    const float* __restrict__ coords,     // V x 3
    const float* __restrict__ distsq,     // V x K
    const _Float16* __restrict__ plane_lo,// V x 16
    const _Float16* __restrict__ plane_hi,// V x 16
    const int*   __restrict__ nidx,       // V x K
    float* __restrict__ out,              // V x 384
    int V)
{
    __shared__ float4  s_wxyz[VPB * WSTRIDE]; // (w,x,y,z), padded stride 10496 B
    __shared__ int     s_joff[PAIRS];         // j*16 plane row offset    2560 B
    __shared__ floatx4 s_stage[STAGE_F4];     // half-output stage       12288 B

    const int tid   = threadIdx.x;
    const int vbase = blockIdx.x * VPB;
    const long long total_pairs = (long long)V * K;

    // ---- Phase 1: stage weights/coords, 640 pairs (streams read ONCE) ----
    for (int p = tid; p < PAIRS; p += 256) {
        const long long gp = (long long)vbase * K + p;
        int idx = -1;
        float d = 0.f;
        if (gp < total_pairs) {
            idx = __builtin_nontemporal_load(nidx + gp);    // coalesced, single-use
            d   = __builtin_nontemporal_load(distsq + gp);  // coalesced, single-use
        }
        const bool valid = (idx >= 0);
        const int j = valid ? idx : 0;
        const float w = valid ? __expf(-DIST_SCALE * d) : 0.f;  // w==0 = invalid
        const float x = coords[(size_t)j * 3 + 0];
        const float y = coords[(size_t)j * 3 + 1];
        const float z = coords[(size_t)j * 3 + 2];
        const int vloc = p / K, k = p - vloc * K;
        s_wxyz[vloc * WSTRIDE + k] = make_float4(w, x, y, z);
        s_joff[p] = j * FH;
    }
    __syncthreads();

    // ---- Passes A/B: lane = (vertex, feature-slot within half) ----
    const int fl   = tid & 15;   // feature slot within half
    const int vloc = tid >> 4;   // 0..15
    const float4* wp = &s_wxyz[vloc * WSTRIDE];
    const int*    jp = &s_joff[vloc * K];
    const int rem_v = V - vbase;          // >= 1
    floatx4* o4 = (floatx4*)(out + (size_t)vbase * OUT_PER_V);

    #pragma unroll
    for (int half = 0; half < 2; ++half) {
        const _Float16* __restrict__ plane = half ? plane_hi : plane_lo;

        float wsum = 0.f;
        float m0 = 0.f, m1 = 0.f, m2 = 0.f;
        float s00 = 0.f, s01 = 0.f, s02 = 0.f, s11 = 0.f, s12 = 0.f, s22 = 0.f;

        #pragma unroll 8
        for (int k = 0; k < K; ++k) {
            const float4 q = wp[k];         // b128 broadcast, banks 4*vloc..+3: free
            const int jo   = jp[k];         // broadcast, banks 8*vloc mod 32: free
            const float feat = (float)plane[jo + fl];  // 32B plane-row gather
            const float fw = q.x * feat;    // w==0 encodes invalid neighbor
            const float x = q.y, y = q.z, z = q.w;
            const float fx = fw * x, fy = fw * y, fz = fw * z;
            wsum += fw;
            m0 += fx;        m1 += fy;        m2 += fz;
            s00 += fx * x;   s01 += fx * y;   s02 += fx * z;
            s11 += fy * y;   s12 += fy * z;   s22 += fz * z;
        }

        const float inv = 1.f / (wsum + EPS);
        const float mu0 = m0 * inv, mu1 = m1 * inv, mu2 = m2 * inv;
        const float c00 = s00 * inv - mu0 * mu0;
        const float c01 = s01 * inv - mu0 * mu1;
        const float c02 = s02 * inv - mu0 * mu2;
        const float c11 = s11 * inv - mu1 * mu1;
        const float c12 = s12 * inv - mu1 * mu2;
        const float c22 = s22 * inv - mu2 * mu2;

        // Stage this half's results: per vertex 192 floats = [cov 144 | mean 48]
        float* s_out = (float*)s_stage;
        float* so = s_out + vloc * 192 + fl * 9;
        so[0] = c00; so[1] = c01; so[2] = c02;
        so[3] = c01; so[4] = c11; so[5] = c12;
        so[6] = c02; so[7] = c12; so[8] = c22;
        float* sm = s_out + vloc * 192 + 144 + fl * 3;
        sm[0] = mu0; sm[1] = mu1; sm[2] = mu2;

        __syncthreads();

        // Coalesced NT writeback of this half's regions.
        // Per vertex (96 f4): cov half h -> [h*36, h*36+36); means half h ->
        // [72+h*12, 72+h*12+12).
        #pragma unroll
        for (int g = tid; g < STAGE_F4; g += 256) {
            const int v = g / 48;
            const int r = g - v * 48;
            if (v < rem_v) {
                const int dst = v * 96 + (r < 36 ? half * 36 + r
                                                 : 72 + half * 12 + (r - 36));
                __builtin_nontemporal_store(s_stage[g], o4 + dst);
            }
        }

        __syncthreads();  // s_stage reuse by next half
    }
}

// ---- Fallback: R4 structure, f32 features (95 us known-good) ----
constexpr int VPB8 = 8;
constexpr int PAIRS8 = VPB8 * K;              // 320
constexpr int OUT_F4_8 = VPB8 * OUT_PER_V / 4;// 768

__global__ __launch_bounds__(256) void neighcov_f32(
    const float* __restrict__ coords, const float* __restrict__ distsq,
    const float* __restrict__ features, const int* __restrict__ nidx,
    float* __restrict__ out, int V)
{
    __shared__ float4  s_wxyz[PAIRS8];
    __shared__ int     s_joff[PAIRS8];
    __shared__ floatx4 s_out4[OUT_F4_8];

    const int tid   = threadIdx.x;
    const int vbase = blockIdx.x * VPB8;
    const long long total_pairs = (long long)V * K;

    #pragma unroll
    for (int p = tid; p < PAIRS8; p += 256) {
        const long long gp = (long long)vbase * K + p;
        int idx = -1; float d = 0.f;
        if (gp < total_pairs) {
            idx = __builtin_nontemporal_load(nidx + gp);
            d   = __builtin_nontemporal_load(distsq + gp);
        }
        const bool valid = (idx >= 0);
        const int j = valid ? idx : 0;
        const float w = valid ? __expf(-DIST_SCALE * d) : 0.f;
        s_wxyz[p] = make_float4(w, coords[(size_t)j * 3 + 0],
                                coords[(size_t)j * 3 + 1], coords[(size_t)j * 3 + 2]);
        s_joff[p] = j * F;
    }
    __syncthreads();

    const int f = tid & (F - 1), vloc = tid >> 5;
    const float4* wp = &s_wxyz[vloc * K];
    const int*    jp = &s_joff[vloc * K];

    float wsum = 0.f, m0 = 0.f, m1 = 0.f, m2 = 0.f;
    float s00 = 0.f, s01 = 0.f, s02 = 0.f, s11 = 0.f, s12 = 0.f, s22 = 0.f;
    #pragma unroll 8
    for (int k = 0; k < K; ++k) {
        const float4 q = wp[k];
        const float feat = features[jp[k] + f];
        const float fw = q.x * feat;
        const float x = q.y, y = q.z, z = q.w;
        const float fx = fw * x, fy = fw * y, fz = fw * z;
        wsum += fw; m0 += fx; m1 += fy; m2 += fz;
        s00 += fx * x; s01 += fx * y; s02 += fx * z;
        s11 += fy * y; s12 += fy * z; s22 += fz * z;
    }
    const float inv = 1.f / (wsum + EPS);
    const float mu0 = m0 * inv, mu1 = m1 * inv, mu2 = m2 * inv;
    float* s_out = (float*)s_out4;
    float* so = s_out + vloc * OUT_PER_V + f * 9;
    so[0] = s00 * inv - mu0 * mu0; so[1] = s01 * inv - mu0 * mu1;
    so[2] = s02 * inv - mu0 * mu2; so[3] = so[1];
    so[4] = s11 * inv - mu1 * mu1; so[5] = s12 * inv - mu1 * mu2;
    so[6] = so[2]; so[7] = so[5]; so[8] = s22 * inv - mu2 * mu2;
    float* sm = s_out + vloc * OUT_PER_V + F * 9 + f * 3;
    sm[0] = mu0; sm[1] = mu1; sm[2] = mu2;
    __syncthreads();

    const int rem_v = V - vbase;
    const int lim_f4 = (rem_v >= VPB8) ? OUT_F4_8 : rem_v * (OUT_PER_V / 4);
    floatx4* o4 = (floatx4*)(out + (size_t)vbase * OUT_PER_V);
    #pragma unroll
    for (int g = tid; g < OUT_F4_8; g += 256)
        if (g < lim_f4) __builtin_nontemporal_store(s_out4[g], o4 + g);
}

extern "C" void kernel_launch(void* const* d_in, const int* in_sizes, int n_in,
                              void* d_out, int out_size, void* d_ws, size_t ws_size,
                              hipStream_t stream) {
    const float* coords   = (const float*)d_in[0];
    const float* distsq   = (const float*)d_in[1];
    const float* features = (const float*)d_in[2];
    const int*   nidx     = (const int*)d_in[3];
    float* out = (float*)d_out;

    const int V = in_sizes[0] / C;            // coordinates is V x 3

    const size_t plane_bytes = (size_t)V * FH * sizeof(_Float16);
    if (ws_size >= 2 * plane_bytes) {
        _Float16* lo = (_Float16*)d_ws;
        _Float16* hi = lo + (size_t)V * FH;
        const int n4 = V * 4;
        cvt_kernel<<<(n4 + 255) / 256, 256, 0, stream>>>(features, lo, hi, n4);
        const int blocks = (V + VPB - 1) / VPB;
        neighcov_split<<<blocks, 256, 0, stream>>>(
            coords, distsq, lo, hi, nidx, out, V);
    } else {
        const int blocks = (V + VPB8 - 1) / VPB8;
        neighcov_f32<<<blocks, 256, 0, stream>>>(
            coords, distsq, features, nidx, out, V);
    }
}